// Round 20
// baseline (216.494 us; speedup 1.0000x reference)
//
#include <hip/hip_runtime.h>
#include <hip/hip_bf16.h>
#include <stdint.h>

// MHA fused pipeline, MI355X gfx950.
// B=4 S=2048 D=1024 H=16 DK=64.  fp32 in/out, bf16 MFMA internally.
//
// ws layout (bytes):
//   [0,        8388608)   wbf   : bf16 weights [4][1024][1024] order q,k,v,o
//                                 (q-slice doubles as l1/l2 partial storage
//                                  during attn — dead after gemm_qkvv)
//   [8388608,  25165824)  Qh    : bf16 [B,H,S,DK]  (Q pre-scaled by 0.125*log2e)
//   [25165824, 41943040)  Kh    : bf16 [B,H,S,DK]
//   [41943040, 58720256)  Vh    : bf16 [B,H,DK,S]  (TRANSPOSED)
//   [58720256, 75497472)  AO    : bf16, DUAL USE: Xq staging -> attn output
// d_out (33.5MB fp32): Xk/Xv bf16 scratch during QKV phase, then partial
// O1/O2 (bf16, 16.77MB each = exactly 2 halves) during attn; fully
// overwritten by gemm_out at the end (deterministic).
//
// Round 20: attn KV-SPLIT — grid (8,64,2), z = half of KV range. Block
// internals byte-identical to the proven v7 (rounds 17/18 showed changing
// block internals loses); only the kv loop range and the epilogue (partial
// bf16 O + f32 l, no divide) differ. combine_kernel: AO=(O1+O2)/(l1+l2).
// No max-sub softmax => partials combine by plain addition.
//
// NUMERICS: ALL f32->bf16 casts use explicit RNE bit math. v_cvt_pk_bf16_f32
// is NOT RNE (rounds 7/13). RULE#20: no runtime-indexed register arrays.
// Softmax denominator = MFMA row-sum (ones-B) of the SAME rounded P.

using f32x4  = __attribute__((ext_vector_type(4))) float;
using f32x16 = __attribute__((ext_vector_type(16))) float;
using s16x8  = __attribute__((ext_vector_type(8))) short;
using u16x8  = __attribute__((ext_vector_type(8))) unsigned short;
using u16x4  = __attribute__((ext_vector_type(4))) unsigned short;

#define MFMA16(a, b, c) __builtin_amdgcn_mfma_f32_16x16x32_bf16((a), (b), (c), 0, 0, 0)
#define MFMA32(a, b, c) __builtin_amdgcn_mfma_f32_32x32x16_bf16((a), (b), (c), 0, 0, 0)

#define GLL16(gptr, lptr)                                                      \
  __builtin_amdgcn_global_load_lds(                                            \
      (const __attribute__((address_space(1))) void*)(gptr),                   \
      (__attribute__((address_space(3))) void*)(lptr), 16, 0, 0)

__device__ __forceinline__ unsigned short f2bf(float f) {
  union { __hip_bfloat16 h; unsigned short u; } cv;
  cv.h = __float2bfloat16(f);
  return cv.u;
}

// explicit RNE f32->bf16 pair pack (bit-identical to __float2bfloat16, finite)
__device__ __forceinline__ unsigned int pkrne(float a, float b) {
  unsigned int ua = __builtin_bit_cast(unsigned int, a);
  unsigned int ub = __builtin_bit_cast(unsigned int, b);
  ua = ua + 0x7FFFu + ((ua >> 16) & 1u);
  ub = ub + 0x7FFFu + ((ub >> 16) & 1u);
  return __builtin_amdgcn_perm(ub, ua, 0x07060302u);
}

__device__ __forceinline__ float bf2f(unsigned short u) {
  return __builtin_bit_cast(float, (unsigned int)u << 16);
}

__device__ __forceinline__ float exp2a(float x) {
  return __builtin_amdgcn_exp2f(x);
}

// --------------------------------------------------------------- cast (merged)
__global__ __launch_bounds__(256) void cast_all_kernel(
    const float* __restrict__ wq, const float* __restrict__ wk,
    const float* __restrict__ wv, const float* __restrict__ wo,
    const float* __restrict__ xq, const float* __restrict__ xk,
    const float* __restrict__ xv, unsigned short* __restrict__ wbf,
    unsigned short* __restrict__ oxq, unsigned short* __restrict__ oxk,
    unsigned short* __restrict__ oxv) {
  const int job = blockIdx.y;
  const int i = blockIdx.x * 256 + threadIdx.x;  // float4 idx within slice
  const float* src;
  unsigned short* dst;
  size_t off;
  if (job < 4) {
    src = (job == 0) ? wq : (job == 1) ? wk : (job == 2) ? wv : wo;
    dst = wbf + (size_t)job * 1048576;
    off = (size_t)i;
  } else {
    const int xi = job - 4, z = xi >> 3, sl = xi & 7;
    src = (z == 0) ? xq : (z == 1) ? xk : xv;
    dst = (z == 0) ? oxq : (z == 1) ? oxk : oxv;
    off = (size_t)sl * 262144 + i;
  }
  float4 f = reinterpret_cast<const float4*>(src)[off];
  uint2 p;
  p.x = pkrne(f.x, f.y);
  p.y = pkrne(f.z, f.w);
  *reinterpret_cast<uint2*>(dst + off * 4) = p;
}

// ---------------------------------------------- Q/K/V projection (merged, bf16)
// z in {0,1}: C = Xbf @ W^T + bias -> [B,H,S,DK] scatter (Q scaled).
// z == 2  : V^T via swapped MFMA operands -> Vh[B,H,DK,S] coalesced.
// BK=64, GLL16 both operands, chunk swizzle phys = logical ^ (row&7).
__global__ __launch_bounds__(256) void gemm_qkvv_kernel(
    const unsigned short* __restrict__ Xq, const unsigned short* __restrict__ Xk,
    const unsigned short* __restrict__ Xv, const unsigned short* __restrict__ wbf,
    const float* __restrict__ bq, const float* __restrict__ bk,
    const float* __restrict__ bv, unsigned short* __restrict__ Qh,
    unsigned short* __restrict__ Kh, unsigned short* __restrict__ Vh) {
  const int z = blockIdx.z;
  const unsigned short* Xbf = (z == 0) ? Xq : (z == 1) ? Xk : Xv;
  const unsigned short* W = wbf + (size_t)z * 1048576;
  const float* bias = (z == 0) ? bq : (z == 1) ? bk : bv;
  const float qscale = (z == 0) ? 0.18033688011112042f : 1.0f;  // 0.125*log2e

  __shared__ __align__(16) unsigned short Asm_[128 * 64];
  __shared__ __align__(16) unsigned short Bsm_[128 * 64];

  const int t = threadIdx.x;
  const int lane = t & 63, w = t >> 6;
  const int g = lane >> 4, c = lane & 15;
  const int wm = (w >> 1) * 64, wn = (w & 1) * 64;
  const int n0 = (blockIdx.y & 7) * 128;
  const int m0 = (blockIdx.x * 8 + (blockIdx.y >> 3)) * 128;

  f32x4 acc[4][4];
#pragma unroll
  for (int i = 0; i < 4; i++)
#pragma unroll
    for (int j = 0; j < 4; j++) acc[i][j] = (f32x4)0.0f;

  const int blr = lane >> 3;
  const int bgc = (lane & 7) ^ blr;

  for (int kt = 0; kt < 16; ++kt) {
    const int k0 = kt * 64;
    __syncthreads();
#pragma unroll
    for (int i = 0; i < 4; i++) {
      int ii = w * 4 + i;
      const unsigned short* ga = Xbf + (size_t)(m0 + ii * 8 + blr) * 1024 + k0 + bgc * 8;
      GLL16(ga, &Asm_[ii * 512]);
      const unsigned short* gb = W + (size_t)(n0 + ii * 8 + blr) * 1024 + k0 + bgc * 8;
      GLL16(gb, &Bsm_[ii * 512]);
    }
    __syncthreads();

#pragma unroll
    for (int ks = 0; ks < 2; ks++) {
      s16x8 af[4], bfr[4];
#pragma unroll
      for (int mt = 0; mt < 4; mt++) {
        int r = wm + mt * 16 + c;
        af[mt] = *reinterpret_cast<const s16x8*>(&Asm_[r * 64 + (((ks * 4 + g) ^ (c & 7)) << 3)]);
      }
#pragma unroll
      for (int nt = 0; nt < 4; nt++) {
        int r = wn + nt * 16 + c;
        bfr[nt] = *reinterpret_cast<const s16x8*>(&Bsm_[r * 64 + (((ks * 4 + g) ^ (c & 7)) << 3)]);
      }
      if (z == 2) {
        // transposed: D[n][m]
#pragma unroll
        for (int nt = 0; nt < 4; nt++)
#pragma unroll
          for (int mt = 0; mt < 4; mt++)
            acc[nt][mt] = MFMA16(bfr[nt], af[mt], acc[nt][mt]);
      } else {
#pragma unroll
        for (int mt = 0; mt < 4; mt++)
#pragma unroll
          for (int nt = 0; nt < 4; nt++)
            acc[mt][nt] = MFMA16(af[mt], bfr[nt], acc[mt][nt]);
      }
    }
  }

  if (z == 2) {
    // epilogue: +bias, write Vh[B,H,DK,S]; lanes (c) -> consecutive s.
#pragma unroll
    for (int nt = 0; nt < 4; nt++)
#pragma unroll
      for (int mt = 0; mt < 4; mt++) {
        int m = m0 + wm + mt * 16 + c;   // global s index
        int b = m >> 11, s = m & 2047;
#pragma unroll
        for (int r = 0; r < 4; r++) {
          int n = n0 + wn + nt * 16 + g * 4 + r;  // feature
          int h = n >> 6, dk = n & 63;
          Vh[(((size_t)b * 16 + h) * 64 + dk) * 2048 + s] =
              f2bf(acc[nt][mt][r] + bv[n]);
        }
      }
  } else {
    unsigned short* dst = (z == 0) ? Qh : Kh;
#pragma unroll
    for (int mt = 0; mt < 4; mt++)
#pragma unroll
      for (int nt = 0; nt < 4; nt++) {
        int n = n0 + wn + nt * 16 + c;
        float bb = bias[n];
        int h = n >> 6, dk = n & 63;
#pragma unroll
        for (int r = 0; r < 4; r++) {
          int m = m0 + wm + mt * 16 + g * 4 + r;
          int b = m >> 11, s = m & 2047;
          dst[(((size_t)b * 16 + h) * 2048 + s) * 64 + dk] =
              f2bf((acc[mt][nt][r] + bb) * qscale);
        }
      }
  }
}

// ----------------------------------------------------------- output projection
// out(fp32)[8192,1024] = AO(bf16) @ Wo(bf16,[N,K]) + bo.  128x64 tile.
__global__ __launch_bounds__(256) void gemm_out_kernel(
    const unsigned short* __restrict__ AO, const unsigned short* __restrict__ Wo,
    const float* __restrict__ bo, float* __restrict__ out) {
  __shared__ __align__(16) unsigned short Asm_[128 * 64];
  __shared__ __align__(16) unsigned short Bsm_[64 * 64];

  const int t = threadIdx.x;
  const int lane = t & 63, w = t >> 6;
  const int g = lane >> 4, c = lane & 15;
  const int wm = (w >> 1) * 64, wn = (w & 1) * 32;
  const int n0 = (blockIdx.y & 15) * 64;
  const int m0 = (blockIdx.x * 8 + (blockIdx.y >> 4)) * 128;

  f32x4 acc[4][2];
#pragma unroll
  for (int i = 0; i < 4; i++)
#pragma unroll
    for (int j = 0; j < 2; j++) acc[i][j] = (f32x4)0.0f;

  const int blr = lane >> 3;
  const int bgc = (lane & 7) ^ blr;

  for (int kt = 0; kt < 16; ++kt) {
    const int k0 = kt * 64;
    __syncthreads();
#pragma unroll
    for (int i = 0; i < 4; i++) {
      int ii = w * 4 + i;
      const unsigned short* ga = AO + (size_t)(m0 + ii * 8 + blr) * 1024 + k0 + bgc * 8;
      GLL16(ga, &Asm_[ii * 512]);
    }
#pragma unroll
    for (int i = 0; i < 2; i++) {
      int ii = w * 2 + i;
      const unsigned short* gb = Wo + (size_t)(n0 + ii * 8 + blr) * 1024 + k0 + bgc * 8;
      GLL16(gb, &Bsm_[ii * 512]);
    }
    __syncthreads();

#pragma unroll
    for (int ks = 0; ks < 2; ks++) {
      s16x8 af[4], bfr[2];
#pragma unroll
      for (int mt = 0; mt < 4; mt++) {
        int r = wm + mt * 16 + c;
        af[mt] = *reinterpret_cast<const s16x8*>(&Asm_[r * 64 + (((ks * 4 + g) ^ (c & 7)) << 3)]);
      }
#pragma unroll
      for (int nt = 0; nt < 2; nt++) {
        int r = wn + nt * 16 + c;
        bfr[nt] = *reinterpret_cast<const s16x8*>(&Bsm_[r * 64 + (((ks * 4 + g) ^ (c & 7)) << 3)]);
      }
#pragma unroll
      for (int mt = 0; mt < 4; mt++)
#pragma unroll
        for (int nt = 0; nt < 2; nt++)
          acc[mt][nt] = MFMA16(af[mt], bfr[nt], acc[mt][nt]);
    }
  }

#pragma unroll
  for (int mt = 0; mt < 4; mt++)
#pragma unroll
    for (int nt = 0; nt < 2; nt++) {
      int n = n0 + wn + nt * 16 + c;
      float bb = bo[n];
#pragma unroll
      for (int r = 0; r < 4; r++) {
        int m = m0 + wm + mt * 16 + g * 4 + r;
        out[(size_t)m * 1024 + n] = acc[mt][nt][r] + bb;
      }
    }
}

// --------------------------------------------------------------- attention v10
// v7 block internals (verbatim) + KV-split: grid (8,64,2), z = kv half.
// Each block runs 16 KV tiles and writes UNNORMALIZED partial O (bf16) to its
// d_out half + partial l (f32). combine_kernel finishes the softmax ratio.
__global__ __launch_bounds__(512) void attn_kernel(
    const unsigned short* __restrict__ Qh, const unsigned short* __restrict__ Kh,
    const unsigned short* __restrict__ Vh, unsigned short* __restrict__ Opart,
    float* __restrict__ lw) {
  const int bh = blockIdx.x * 8 + (blockIdx.y >> 3);
  const int b = bh >> 4, h = bh & 15;
  const int q0 = (blockIdx.y & 7) * 256;
  const int kvh = blockIdx.z;
  const int t = threadIdx.x, lane = t & 63, w = t >> 6;
  const int lo = lane & 31, hi = lane >> 5;

  __shared__ __align__(16) unsigned short Ks[2][64 * 64];
  __shared__ __align__(16) unsigned short Vs[2][64 * 64];

  const size_t kvbase = (size_t)bh * 2048 * 64;

  s16x8 qb[4];
  {
    const unsigned short* qp = Qh + kvbase + (size_t)(q0 + w * 32 + lo) * 64;
#pragma unroll
    for (int ks = 0; ks < 4; ks++)
      qb[ks] = *reinterpret_cast<const s16x8*>(qp + ks * 16 + hi * 8);
  }

  s16x8 onesb;
  {
    uint4 u;
    u.x = 0x3F803F80u; u.y = 0x3F803F80u; u.z = 0x3F803F80u; u.w = 0x3F803F80u;
    onesb = *reinterpret_cast<const s16x8*>(&u);
  }

  f32x16 oacc[2], lacc;
  oacc[0] = (f32x16)0.0f; oacc[1] = (f32x16)0.0f; lacc = (f32x16)0.0f;

  const int srow = t >> 3;
  const int gch = (t & 7) ^ (srow & 7) ^ w;      // srow>>3 == w
  const unsigned short* Kg = Kh + kvbase + (size_t)srow * 64 + gch * 8;
  const unsigned short* Vg = Vh + kvbase + (size_t)srow * 2048 + gch * 8;

  const int rx0 = (lo & 7) ^ (lo >> 3);
  const int rx1 = (lo & 7) ^ (4 | (lo >> 3));

  const int t0 = kvh * 16;  // first tile of this half

  // prologue: first tile -> buf 0 (vmcnt drained by the barrier)
  GLL16(Kg + (size_t)t0 * 4096, &Ks[0][w * 512]);
  GLL16(Vg + t0 * 64, &Vs[0][w * 512]);
  __syncthreads();

  for (int it = 0; it < 16; ++it) {
    const int cur = it & 1;
    if (it < 15) {
      const int tile = t0 + it + 1;
      GLL16(Kg + (size_t)tile * 4096, &Ks[cur ^ 1][w * 512]);
      GLL16(Vg + tile * 64, &Vs[cur ^ 1][w * 512]);
    }

    // S^T = K·Q^T
    f32x16 st[2];
    st[0] = (f32x16)0.0f; st[1] = (f32x16)0.0f;
#pragma unroll
    for (int kb = 0; kb < 2; kb++) {
      const int rx = kb ? rx1 : rx0;
#pragma unroll
      for (int ks = 0; ks < 4; ks++) {
        s16x8 ka = *reinterpret_cast<const s16x8*>(
            &Ks[cur][(kb * 32 + lo) * 64 + (((ks * 2 + hi) ^ rx) << 3)]);
        st[kb] = MFMA32(ka, qb[ks], st[kb]);
      }
    }

    // p = 2^s -> RNE bf16 pack -> permlane swap -> PV A-frags
    s16x8 pa[4];
#pragma unroll
    for (int kb = 0; kb < 2; kb++) {
      float e[16];
#pragma unroll
      for (int r = 0; r < 16; r++) e[r] = exp2a(st[kb][r]);
#pragma unroll
      for (int half = 0; half < 2; half++) {
        const float* eb = e + half * 8;
        unsigned int x1 = pkrne(eb[0], eb[1]);
        unsigned int x2 = pkrne(eb[2], eb[3]);
        unsigned int y1 = pkrne(eb[4], eb[5]);
        unsigned int y2 = pkrne(eb[6], eb[7]);
        asm volatile("v_permlane32_swap_b32 %0, %1" : "+v"(x1), "+v"(y1));
        asm volatile("v_permlane32_swap_b32 %0, %1" : "+v"(x2), "+v"(y2));
        uint4 u;
        u.x = x1; u.y = x2; u.z = y1; u.w = y2;
        pa[kb * 2 + half] = *reinterpret_cast<const s16x8*>(&u);
      }
    }

    // denominator: row-sum of packed P via MFMA
#pragma unroll
    for (int ks = 0; ks < 4; ks++) lacc = MFMA32(pa[ks], onesb, lacc);

    // O += P·V
#pragma unroll
    for (int ks = 0; ks < 4; ks++)
#pragma unroll
      for (int db = 0; db < 2; db++) {
        const int rx = db ? rx1 : rx0;
        s16x8 vb = *reinterpret_cast<const s16x8*>(
            &Vs[cur][(db * 32 + lo) * 64 + (((ks * 2 + hi) ^ rx) << 3)]);
        oacc[db] = MFMA32(pa[ks], vb, oacc[db]);
      }

    __syncthreads();  // drains next-tile DMA; protects cur for reuse
  }

  // epilogue: write UNNORMALIZED partial O (bf16) + partial l (f32)
  unsigned short* Op = Opart + (size_t)kvh * 8388608;
  float* lp = lw + ((size_t)kvh << 17);
#pragma unroll
  for (int r = 0; r < 16; r++) {
    int qr = (r & 3) + ((r >> 2) << 3) + (hi << 2);
    int srow_q = q0 + w * 32 + qr;
    size_t obase = ((size_t)b * 2048 + srow_q) * 1024 + (size_t)h * 64;
    Op[obase + lo]      = f2bf(oacc[0][r]);
    Op[obase + 32 + lo] = f2bf(oacc[1][r]);
    if (lo == 0) lp[(size_t)bh * 2048 + srow_q] = lacc[r];
  }
}

// ------------------------------------------------------------------- combine
// AO[b,s,d] = (O1 + O2) / (l1 + l2).  8 bf16 elems/thread (one h-block each).
__global__ __launch_bounds__(256) void combine_kernel(
    const unsigned short* __restrict__ O1, const unsigned short* __restrict__ O2,
    const float* __restrict__ l1, const float* __restrict__ l2,
    unsigned short* __restrict__ AO) {
  size_t i = ((size_t)blockIdx.x * 256 + threadIdx.x) * 8;
  int d = (int)(i & 1023);
  int s = (int)((i >> 10) & 2047);
  int b = (int)(i >> 21);
  int h = d >> 6;
  size_t li = ((size_t)(b * 16 + h) << 11) + s;
  float inv = 1.0f / (l1[li] + l2[li]);
  u16x8 a = *reinterpret_cast<const u16x8*>(O1 + i);
  u16x8 c = *reinterpret_cast<const u16x8*>(O2 + i);
  u16x8 o;
#pragma unroll
  for (int j = 0; j < 8; j++) {
    float fa = __builtin_bit_cast(float, (unsigned int)a[j] << 16);
    float fc = __builtin_bit_cast(float, (unsigned int)c[j] << 16);
    o[j] = f2bf((fa + fc) * inv);
  }
  *reinterpret_cast<u16x8*>(AO + i) = o;
}

// ---------------------------------------------------------------- launcher
extern "C" void kernel_launch(void* const* d_in, const int* in_sizes, int n_in,
                              void* d_out, int out_size, void* d_ws, size_t ws_size,
                              hipStream_t stream) {
  const float* query = (const float*)d_in[0];
  const float* key   = (const float*)d_in[1];
  const float* value = (const float*)d_in[2];
  const float* Wq = (const float*)d_in[3];
  const float* bq = (const float*)d_in[4];
  const float* Wk = (const float*)d_in[5];
  const float* bk = (const float*)d_in[6];
  const float* Wv = (const float*)d_in[7];
  const float* bv = (const float*)d_in[8];
  const float* Wo = (const float*)d_in[9];
  const float* bo = (const float*)d_in[10];

  uint8_t* wsb = (uint8_t*)d_ws;
  unsigned short* wbf = (unsigned short*)wsb;                      // 4 x 1M bf16
  unsigned short* Qh  = (unsigned short*)(wsb + 8388608);
  unsigned short* Kh  = (unsigned short*)(wsb + 8388608 + 16777216);
  unsigned short* Vh  = (unsigned short*)(wsb + 8388608 + 2 * 16777216);
  unsigned short* AO  = (unsigned short*)(wsb + 8388608 + 3 * 16777216);
  // bf16 X staging: Xq in AO region; Xk/Xv in d_out (scratch until attn)
  unsigned short* Xq = AO;
  unsigned short* Xk = (unsigned short*)d_out;
  unsigned short* Xv = (unsigned short*)d_out + 8388608;
  // attn partials: O1/O2 bf16 fill d_out exactly; l1/l2 in dead q-weight slice
  unsigned short* Opart = (unsigned short*)d_out;
  float* lw = (float*)wbf;   // 2 x 131072 floats = 1MB << 2MB slice

  cast_all_kernel<<<dim3(1024, 28), dim3(256), 0, stream>>>(
      Wq, Wk, Wv, Wo, query, key, value, wbf, Xq, Xk, Xv);
  gemm_qkvv_kernel<<<dim3(8, 64, 3), dim3(256), 0, stream>>>(
      Xq, Xk, Xv, wbf, bq, bk, bv, Qh, Kh, Vh);
  attn_kernel<<<dim3(8, 64, 2), dim3(512), 0, stream>>>(Qh, Kh, Vh, Opart, lw);
  combine_kernel<<<dim3(4096), dim3(256), 0, stream>>>(
      Opart, Opart + 8388608, lw, lw + 131072, AO);
  gemm_out_kernel<<<dim3(8, 128), dim3(256), 0, stream>>>(
      AO, wbf + (size_t)3 * 1048576, bo, (float*)d_out);
}

// Round 21
// 201.679 us; speedup vs baseline: 1.0735x; 1.0735x over previous
//
#include <hip/hip_runtime.h>
#include <hip/hip_bf16.h>
#include <stdint.h>

// MHA fused pipeline, MI355X gfx950.
// B=4 S=2048 D=1024 H=16 DK=64.  fp32 in/out, bf16 MFMA internally.
//
// ws layout (bytes):
//   [0,        8388608)   wbf   : bf16 weights [4][1024][1024] order q,k,v,o
//   [8388608,  25165824)  Qh    : bf16 [B,H,S,DK]  (Q pre-scaled by 0.125*log2e)
//   [25165824, 41943040)  Kh    : bf16 [B,H,S,DK]
//   [41943040, 58720256)  Vh    : bf16 [B,H,DK,S]  (TRANSPOSED)
//   [58720256, 75497472)  AO    : bf16, DUAL USE: Xq staging -> attn output
// d_out (fp32) is scratch for Xk/Xv bf16 during the QKV phase; fully
// overwritten by gemm_out at the end (deterministic).
//
// Round 21: attn P-pack switched from 7-op RNE bit math to 3-op
// (+0x8000 integer bias -> truncating v_cvt_pk_bf16_f32) = ROUND-HALF-UP.
// Rationale: round-20's KV-split left attn EXACTLY at 94us with 2x blocks ->
// throughput-bound; VALUBusy 53% issue at 2cyc/instr ~= VALU pipe saturated.
// Round-half-up differs from RNE only on exact-half mantissas (2^-16 prob,
// 1 ulp) — unlike round-13's one-sided truncation (which failed). P>0 always.
// KV-split + combine REVERTED (throughput-bound => partitioning is neutral,
// overhead is not). Everything else = round-19 best (206.9us).
//
// NUMERICS elsewhere: ALL f32->bf16 casts use explicit RNE bit math.
// RULE#20: no runtime-indexed register arrays. Softmax denominator = MFMA
// row-sum (ones-B) of the SAME rounded P.

using f32x4  = __attribute__((ext_vector_type(4))) float;
using f32x16 = __attribute__((ext_vector_type(16))) float;
using s16x8  = __attribute__((ext_vector_type(8))) short;
using u16x8  = __attribute__((ext_vector_type(8))) unsigned short;
using u16x4  = __attribute__((ext_vector_type(4))) unsigned short;

#define MFMA16(a, b, c) __builtin_amdgcn_mfma_f32_16x16x32_bf16((a), (b), (c), 0, 0, 0)
#define MFMA32(a, b, c) __builtin_amdgcn_mfma_f32_32x32x16_bf16((a), (b), (c), 0, 0, 0)

#define GLL16(gptr, lptr)                                                      \
  __builtin_amdgcn_global_load_lds(                                            \
      (const __attribute__((address_space(1))) void*)(gptr),                   \
      (__attribute__((address_space(3))) void*)(lptr), 16, 0, 0)

__device__ __forceinline__ unsigned short f2bf(float f) {
  union { __hip_bfloat16 h; unsigned short u; } cv;
  cv.h = __float2bfloat16(f);
  return cv.u;
}

// explicit RNE f32->bf16 pair pack (bit-identical to __float2bfloat16, finite)
__device__ __forceinline__ unsigned int pkrne(float a, float b) {
  unsigned int ua = __builtin_bit_cast(unsigned int, a);
  unsigned int ub = __builtin_bit_cast(unsigned int, b);
  ua = ua + 0x7FFFu + ((ua >> 16) & 1u);
  ub = ub + 0x7FFFu + ((ub >> 16) & 1u);
  return __builtin_amdgcn_perm(ub, ua, 0x07060302u);
}

// round-half-up f32->bf16 pair pack for POSITIVE finite values: integer
// +0x8000 bias, then truncating v_cvt_pk_bf16_f32. 3 VALU ops vs pkrne's 7.
// Differs from RNE only when low 16 bits == 0x8000 exactly (1 ulp).
__device__ __forceinline__ unsigned int pkhu(float a, float b) {
  unsigned int ua = __builtin_bit_cast(unsigned int, a) + 0x8000u;
  unsigned int ub = __builtin_bit_cast(unsigned int, b) + 0x8000u;
  unsigned int r;
  asm("v_cvt_pk_bf16_f32 %0, %1, %2"
      : "=v"(r)
      : "v"(__builtin_bit_cast(float, ua)), "v"(__builtin_bit_cast(float, ub)));
  return r;
}

__device__ __forceinline__ float exp2a(float x) {
  return __builtin_amdgcn_exp2f(x);
}

// --------------------------------------------------------------- cast (merged)
__global__ __launch_bounds__(256) void cast_all_kernel(
    const float* __restrict__ wq, const float* __restrict__ wk,
    const float* __restrict__ wv, const float* __restrict__ wo,
    const float* __restrict__ xq, const float* __restrict__ xk,
    const float* __restrict__ xv, unsigned short* __restrict__ wbf,
    unsigned short* __restrict__ oxq, unsigned short* __restrict__ oxk,
    unsigned short* __restrict__ oxv) {
  const int job = blockIdx.y;
  const int i = blockIdx.x * 256 + threadIdx.x;  // float4 idx within slice
  const float* src;
  unsigned short* dst;
  size_t off;
  if (job < 4) {
    src = (job == 0) ? wq : (job == 1) ? wk : (job == 2) ? wv : wo;
    dst = wbf + (size_t)job * 1048576;
    off = (size_t)i;
  } else {
    const int xi = job - 4, z = xi >> 3, sl = xi & 7;
    src = (z == 0) ? xq : (z == 1) ? xk : xv;
    dst = (z == 0) ? oxq : (z == 1) ? oxk : oxv;
    off = (size_t)sl * 262144 + i;
  }
  float4 f = reinterpret_cast<const float4*>(src)[off];
  uint2 p;
  p.x = pkrne(f.x, f.y);
  p.y = pkrne(f.z, f.w);
  *reinterpret_cast<uint2*>(dst + off * 4) = p;
}

// ---------------------------------------------- Q/K/V projection (merged, bf16)
// z in {0,1}: C = Xbf @ W^T + bias -> [B,H,S,DK] scatter (Q scaled).
// z == 2  : V^T via swapped MFMA operands -> Vh[B,H,DK,S] coalesced.
// BK=64, GLL16 both operands, chunk swizzle phys = logical ^ (row&7).
__global__ __launch_bounds__(256) void gemm_qkvv_kernel(
    const unsigned short* __restrict__ Xq, const unsigned short* __restrict__ Xk,
    const unsigned short* __restrict__ Xv, const unsigned short* __restrict__ wbf,
    const float* __restrict__ bq, const float* __restrict__ bk,
    const float* __restrict__ bv, unsigned short* __restrict__ Qh,
    unsigned short* __restrict__ Kh, unsigned short* __restrict__ Vh) {
  const int z = blockIdx.z;
  const unsigned short* Xbf = (z == 0) ? Xq : (z == 1) ? Xk : Xv;
  const unsigned short* W = wbf + (size_t)z * 1048576;
  const float* bias = (z == 0) ? bq : (z == 1) ? bk : bv;
  const float qscale = (z == 0) ? 0.18033688011112042f : 1.0f;  // 0.125*log2e

  __shared__ __align__(16) unsigned short Asm_[128 * 64];
  __shared__ __align__(16) unsigned short Bsm_[128 * 64];

  const int t = threadIdx.x;
  const int lane = t & 63, w = t >> 6;
  const int g = lane >> 4, c = lane & 15;
  const int wm = (w >> 1) * 64, wn = (w & 1) * 64;
  const int n0 = (blockIdx.y & 7) * 128;
  const int m0 = (blockIdx.x * 8 + (blockIdx.y >> 3)) * 128;

  f32x4 acc[4][4];
#pragma unroll
  for (int i = 0; i < 4; i++)
#pragma unroll
    for (int j = 0; j < 4; j++) acc[i][j] = (f32x4)0.0f;

  const int blr = lane >> 3;
  const int bgc = (lane & 7) ^ blr;

  for (int kt = 0; kt < 16; ++kt) {
    const int k0 = kt * 64;
    __syncthreads();
#pragma unroll
    for (int i = 0; i < 4; i++) {
      int ii = w * 4 + i;
      const unsigned short* ga = Xbf + (size_t)(m0 + ii * 8 + blr) * 1024 + k0 + bgc * 8;
      GLL16(ga, &Asm_[ii * 512]);
      const unsigned short* gb = W + (size_t)(n0 + ii * 8 + blr) * 1024 + k0 + bgc * 8;
      GLL16(gb, &Bsm_[ii * 512]);
    }
    __syncthreads();

#pragma unroll
    for (int ks = 0; ks < 2; ks++) {
      s16x8 af[4], bfr[4];
#pragma unroll
      for (int mt = 0; mt < 4; mt++) {
        int r = wm + mt * 16 + c;
        af[mt] = *reinterpret_cast<const s16x8*>(&Asm_[r * 64 + (((ks * 4 + g) ^ (c & 7)) << 3)]);
      }
#pragma unroll
      for (int nt = 0; nt < 4; nt++) {
        int r = wn + nt * 16 + c;
        bfr[nt] = *reinterpret_cast<const s16x8*>(&Bsm_[r * 64 + (((ks * 4 + g) ^ (c & 7)) << 3)]);
      }
      if (z == 2) {
        // transposed: D[n][m]
#pragma unroll
        for (int nt = 0; nt < 4; nt++)
#pragma unroll
          for (int mt = 0; mt < 4; mt++)
            acc[nt][mt] = MFMA16(bfr[nt], af[mt], acc[nt][mt]);
      } else {
#pragma unroll
        for (int mt = 0; mt < 4; mt++)
#pragma unroll
          for (int nt = 0; nt < 4; nt++)
            acc[mt][nt] = MFMA16(af[mt], bfr[nt], acc[mt][nt]);
      }
    }
  }

  if (z == 2) {
    // epilogue: +bias, write Vh[B,H,DK,S]; lanes (c) -> consecutive s.
#pragma unroll
    for (int nt = 0; nt < 4; nt++)
#pragma unroll
      for (int mt = 0; mt < 4; mt++) {
        int m = m0 + wm + mt * 16 + c;   // global s index
        int b = m >> 11, s = m & 2047;
#pragma unroll
        for (int r = 0; r < 4; r++) {
          int n = n0 + wn + nt * 16 + g * 4 + r;  // feature
          int h = n >> 6, dk = n & 63;
          Vh[(((size_t)b * 16 + h) * 64 + dk) * 2048 + s] =
              f2bf(acc[nt][mt][r] + bv[n]);
        }
      }
  } else {
    unsigned short* dst = (z == 0) ? Qh : Kh;
#pragma unroll
    for (int mt = 0; mt < 4; mt++)
#pragma unroll
      for (int nt = 0; nt < 4; nt++) {
        int n = n0 + wn + nt * 16 + c;
        float bb = bias[n];
        int h = n >> 6, dk = n & 63;
#pragma unroll
        for (int r = 0; r < 4; r++) {
          int m = m0 + wm + mt * 16 + g * 4 + r;
          int b = m >> 11, s = m & 2047;
          dst[(((size_t)b * 16 + h) * 2048 + s) * 64 + dk] =
              f2bf((acc[mt][nt][r] + bb) * qscale);
        }
      }
  }
}

// ----------------------------------------------------------- output projection
// out(fp32)[8192,1024] = AO(bf16) @ Wo(bf16,[N,K]) + bo.  128x64 tile.
__global__ __launch_bounds__(256) void gemm_out_kernel(
    const unsigned short* __restrict__ AO, const unsigned short* __restrict__ Wo,
    const float* __restrict__ bo, float* __restrict__ out) {
  __shared__ __align__(16) unsigned short Asm_[128 * 64];
  __shared__ __align__(16) unsigned short Bsm_[64 * 64];

  const int t = threadIdx.x;
  const int lane = t & 63, w = t >> 6;
  const int g = lane >> 4, c = lane & 15;
  const int wm = (w >> 1) * 64, wn = (w & 1) * 32;
  const int n0 = (blockIdx.y & 15) * 64;
  const int m0 = (blockIdx.x * 8 + (blockIdx.y >> 4)) * 128;

  f32x4 acc[4][2];
#pragma unroll
  for (int i = 0; i < 4; i++)
#pragma unroll
    for (int j = 0; j < 2; j++) acc[i][j] = (f32x4)0.0f;

  const int blr = lane >> 3;
  const int bgc = (lane & 7) ^ blr;

  for (int kt = 0; kt < 16; ++kt) {
    const int k0 = kt * 64;
    __syncthreads();
#pragma unroll
    for (int i = 0; i < 4; i++) {
      int ii = w * 4 + i;
      const unsigned short* ga = AO + (size_t)(m0 + ii * 8 + blr) * 1024 + k0 + bgc * 8;
      GLL16(ga, &Asm_[ii * 512]);
    }
#pragma unroll
    for (int i = 0; i < 2; i++) {
      int ii = w * 2 + i;
      const unsigned short* gb = Wo + (size_t)(n0 + ii * 8 + blr) * 1024 + k0 + bgc * 8;
      GLL16(gb, &Bsm_[ii * 512]);
    }
    __syncthreads();

#pragma unroll
    for (int ks = 0; ks < 2; ks++) {
      s16x8 af[4], bfr[2];
#pragma unroll
      for (int mt = 0; mt < 4; mt++) {
        int r = wm + mt * 16 + c;
        af[mt] = *reinterpret_cast<const s16x8*>(&Asm_[r * 64 + (((ks * 4 + g) ^ (c & 7)) << 3)]);
      }
#pragma unroll
      for (int nt = 0; nt < 2; nt++) {
        int r = wn + nt * 16 + c;
        bfr[nt] = *reinterpret_cast<const s16x8*>(&Bsm_[r * 64 + (((ks * 4 + g) ^ (c & 7)) << 3)]);
      }
#pragma unroll
      for (int mt = 0; mt < 4; mt++)
#pragma unroll
        for (int nt = 0; nt < 2; nt++)
          acc[mt][nt] = MFMA16(af[mt], bfr[nt], acc[mt][nt]);
    }
  }

#pragma unroll
  for (int mt = 0; mt < 4; mt++)
#pragma unroll
    for (int nt = 0; nt < 2; nt++) {
      int n = n0 + wn + nt * 16 + c;
      float bb = bo[n];
#pragma unroll
      for (int r = 0; r < 4; r++) {
        int m = m0 + wm + mt * 16 + g * 4 + r;
        out[(size_t)m * 1024 + n] = acc[mt][nt][r] + bb;
      }
    }
}

// --------------------------------------------------------------- attention v11
// round-19 v7 structure (512 thr, grid (8,64), GLL16 K+V, ones-MFMA sum);
// only change: P-pack uses pkhu (3 VALU ops) instead of pkrne (7).
__global__ __launch_bounds__(512) void attn_kernel(
    const unsigned short* __restrict__ Qh, const unsigned short* __restrict__ Kh,
    const unsigned short* __restrict__ Vh, unsigned short* __restrict__ AO) {
  const int bh = blockIdx.x * 8 + (blockIdx.y >> 3);
  const int b = bh >> 4, h = bh & 15;
  const int q0 = (blockIdx.y & 7) * 256;
  const int t = threadIdx.x, lane = t & 63, w = t >> 6;
  const int lo = lane & 31, hi = lane >> 5;

  __shared__ __align__(16) unsigned short Ks[2][64 * 64];
  __shared__ __align__(16) unsigned short Vs[2][64 * 64];

  const size_t kvbase = (size_t)bh * 2048 * 64;

  s16x8 qb[4];
  {
    const unsigned short* qp = Qh + kvbase + (size_t)(q0 + w * 32 + lo) * 64;
#pragma unroll
    for (int ks = 0; ks < 4; ks++)
      qb[ks] = *reinterpret_cast<const s16x8*>(qp + ks * 16 + hi * 8);
  }

  s16x8 onesb;
  {
    uint4 u;
    u.x = 0x3F803F80u; u.y = 0x3F803F80u; u.z = 0x3F803F80u; u.w = 0x3F803F80u;
    onesb = *reinterpret_cast<const s16x8*>(&u);
  }

  f32x16 oacc[2], lacc;
  oacc[0] = (f32x16)0.0f; oacc[1] = (f32x16)0.0f; lacc = (f32x16)0.0f;

  const int srow = t >> 3;
  const int gch = (t & 7) ^ (srow & 7) ^ w;      // srow>>3 == w
  const unsigned short* Kg = Kh + kvbase + (size_t)srow * 64 + gch * 8;
  const unsigned short* Vg = Vh + kvbase + (size_t)srow * 2048 + gch * 8;

  const int rx0 = (lo & 7) ^ (lo >> 3);
  const int rx1 = (lo & 7) ^ (4 | (lo >> 3));

  // prologue: tile 0 -> buf 0 (vmcnt drained by the barrier)
  GLL16(Kg, &Ks[0][w * 512]);
  GLL16(Vg, &Vs[0][w * 512]);
  __syncthreads();

  for (int it = 0; it < 32; ++it) {
    const int cur = it & 1;
    if (it < 31) {
      const int kv = (it + 1) * 64;
      GLL16(Kg + (size_t)kv * 64, &Ks[cur ^ 1][w * 512]);
      GLL16(Vg + kv, &Vs[cur ^ 1][w * 512]);
    }

    // S^T = K·Q^T
    f32x16 st[2];
    st[0] = (f32x16)0.0f; st[1] = (f32x16)0.0f;
#pragma unroll
    for (int kb = 0; kb < 2; kb++) {
      const int rx = kb ? rx1 : rx0;
#pragma unroll
      for (int ks = 0; ks < 4; ks++) {
        s16x8 ka = *reinterpret_cast<const s16x8*>(
            &Ks[cur][(kb * 32 + lo) * 64 + (((ks * 2 + hi) ^ rx) << 3)]);
        st[kb] = MFMA32(ka, qb[ks], st[kb]);
      }
    }

    // p = 2^s -> round-half-up bf16 pack (pkhu) -> permlane swap -> PV A-frags
    s16x8 pa[4];
#pragma unroll
    for (int kb = 0; kb < 2; kb++) {
      float e[16];
#pragma unroll
      for (int r = 0; r < 16; r++) e[r] = exp2a(st[kb][r]);
#pragma unroll
      for (int half = 0; half < 2; half++) {
        const float* eb = e + half * 8;
        unsigned int x1 = pkhu(eb[0], eb[1]);
        unsigned int x2 = pkhu(eb[2], eb[3]);
        unsigned int y1 = pkhu(eb[4], eb[5]);
        unsigned int y2 = pkhu(eb[6], eb[7]);
        asm volatile("v_permlane32_swap_b32 %0, %1" : "+v"(x1), "+v"(y1));
        asm volatile("v_permlane32_swap_b32 %0, %1" : "+v"(x2), "+v"(y2));
        uint4 u;
        u.x = x1; u.y = x2; u.z = y1; u.w = y2;
        pa[kb * 2 + half] = *reinterpret_cast<const s16x8*>(&u);
      }
    }

    // denominator: row-sum of packed P via MFMA (same rounded values)
#pragma unroll
    for (int ks = 0; ks < 4; ks++) lacc = MFMA32(pa[ks], onesb, lacc);

    // O += P·V
#pragma unroll
    for (int ks = 0; ks < 4; ks++)
#pragma unroll
      for (int db = 0; db < 2; db++) {
        const int rx = db ? rx1 : rx0;
        s16x8 vb = *reinterpret_cast<const s16x8*>(
            &Vs[cur][(db * 32 + lo) * 64 + (((ks * 2 + hi) ^ rx) << 3)]);
        oacc[db] = MFMA32(pa[ks], vb, oacc[db]);
      }

    __syncthreads();  // drains next-tile DMA; protects cur for reuse
  }

  // epilogue: normalize by lacc (same row layout as oacc), write AO bf16
#pragma unroll
  for (int r = 0; r < 16; r++) {
    float inv_r = 1.0f / lacc[r];
    int qr = (r & 3) + ((r >> 2) << 3) + (hi << 2);
    int srow_q = q0 + w * 32 + qr;
    size_t obase = ((size_t)b * 2048 + srow_q) * 1024 + (size_t)h * 64;
    AO[obase + lo]      = f2bf(oacc[0][r] * inv_r);
    AO[obase + 32 + lo] = f2bf(oacc[1][r] * inv_r);
  }
}

// ---------------------------------------------------------------- launcher
extern "C" void kernel_launch(void* const* d_in, const int* in_sizes, int n_in,
                              void* d_out, int out_size, void* d_ws, size_t ws_size,
                              hipStream_t stream) {
  const float* query = (const float*)d_in[0];
  const float* key   = (const float*)d_in[1];
  const float* value = (const float*)d_in[2];
  const float* Wq = (const float*)d_in[3];
  const float* bq = (const float*)d_in[4];
  const float* Wk = (const float*)d_in[5];
  const float* bk = (const float*)d_in[6];
  const float* Wv = (const float*)d_in[7];
  const float* bv = (const float*)d_in[8];
  const float* Wo = (const float*)d_in[9];
  const float* bo = (const float*)d_in[10];

  uint8_t* wsb = (uint8_t*)d_ws;
  unsigned short* wbf = (unsigned short*)wsb;                      // 4 x 1M bf16
  unsigned short* Qh  = (unsigned short*)(wsb + 8388608);
  unsigned short* Kh  = (unsigned short*)(wsb + 8388608 + 16777216);
  unsigned short* Vh  = (unsigned short*)(wsb + 8388608 + 2 * 16777216);
  unsigned short* AO  = (unsigned short*)(wsb + 8388608 + 3 * 16777216);
  // bf16 X staging: Xq in AO region; Xk/Xv in d_out (scratch until gemm_out)
  unsigned short* Xq = AO;
  unsigned short* Xk = (unsigned short*)d_out;
  unsigned short* Xv = (unsigned short*)d_out + 8388608;

  cast_all_kernel<<<dim3(1024, 28), dim3(256), 0, stream>>>(
      Wq, Wk, Wv, Wo, query, key, value, wbf, Xq, Xk, Xv);
  gemm_qkvv_kernel<<<dim3(8, 64, 3), dim3(256), 0, stream>>>(
      Xq, Xk, Xv, wbf, bq, bk, bv, Qh, Kh, Vh);
  attn_kernel<<<dim3(8, 64), dim3(512), 0, stream>>>(Qh, Kh, Vh, AO);
  gemm_out_kernel<<<dim3(8, 128), dim3(256), 0, stream>>>(
      AO, wbf + (size_t)3 * 1048576, bo, (float*)d_out);
}

// Round 22
// 200.597 us; speedup vs baseline: 1.0792x; 1.0054x over previous
//
#include <hip/hip_runtime.h>
#include <hip/hip_bf16.h>
#include <stdint.h>

// MHA fused pipeline, MI355X gfx950.
// B=4 S=2048 D=1024 H=16 DK=64.  fp32 in/out, bf16 MFMA internally.
//
// ws layout (bytes):
//   [0,        8388608)   wbf   : bf16 weights [4][1024][1024] order q,k,v,o
//   [8388608,  25165824)  Qh    : bf16 [B,H,S,DK]  (Q pre-scaled by 0.125*log2e)
//   [25165824, 41943040)  Kh    : bf16 [B,H,S,DK]
//   [41943040, 58720256)  Vh    : bf16 [B,H,DK,S]  (TRANSPOSED)
//   [58720256, 75497472)  AO    : bf16, DUAL USE: Xq staging -> attn output
// d_out (fp32) is scratch for Xk/Xv bf16 during the QKV phase; fully
// overwritten by gemm_out at the end (deterministic).
//
// Round 22: + T5 s_setprio(1) around attn MFMA clusters (QK; lacc+PV).
// Regime check: 2 independent blocks/CU at different phases -> scheduler has
// something to arbitrate (m191 attn regime, +4-7%), unlike m190's single-
// lockstep-group null. Everything else = round-21 (201.7us best).
//
// NUMERICS: f32->bf16 casts feeding GEMM operands use explicit RNE bit math.
// Attention P uses pkhu = +0x8000 bias + truncating v_cvt_pk_bf16_f32
// (round-half-up; differs from RNE only on exact-half mantissas, P>0) —
// validated round 21 (absmax unchanged 4.88e-4). RULE#20: no runtime-indexed
// register arrays. Softmax denominator = MFMA ones row-sum of the SAME P.

using f32x4  = __attribute__((ext_vector_type(4))) float;
using f32x16 = __attribute__((ext_vector_type(16))) float;
using s16x8  = __attribute__((ext_vector_type(8))) short;
using u16x8  = __attribute__((ext_vector_type(8))) unsigned short;
using u16x4  = __attribute__((ext_vector_type(4))) unsigned short;

#define MFMA16(a, b, c) __builtin_amdgcn_mfma_f32_16x16x32_bf16((a), (b), (c), 0, 0, 0)
#define MFMA32(a, b, c) __builtin_amdgcn_mfma_f32_32x32x16_bf16((a), (b), (c), 0, 0, 0)

#define GLL16(gptr, lptr)                                                      \
  __builtin_amdgcn_global_load_lds(                                            \
      (const __attribute__((address_space(1))) void*)(gptr),                   \
      (__attribute__((address_space(3))) void*)(lptr), 16, 0, 0)

__device__ __forceinline__ unsigned short f2bf(float f) {
  union { __hip_bfloat16 h; unsigned short u; } cv;
  cv.h = __float2bfloat16(f);
  return cv.u;
}

// explicit RNE f32->bf16 pair pack (bit-identical to __float2bfloat16, finite)
__device__ __forceinline__ unsigned int pkrne(float a, float b) {
  unsigned int ua = __builtin_bit_cast(unsigned int, a);
  unsigned int ub = __builtin_bit_cast(unsigned int, b);
  ua = ua + 0x7FFFu + ((ua >> 16) & 1u);
  ub = ub + 0x7FFFu + ((ub >> 16) & 1u);
  return __builtin_amdgcn_perm(ub, ua, 0x07060302u);
}

// round-half-up f32->bf16 pair pack for POSITIVE finite values: integer
// +0x8000 bias, then truncating v_cvt_pk_bf16_f32. 3 VALU ops vs pkrne's 7.
__device__ __forceinline__ unsigned int pkhu(float a, float b) {
  unsigned int ua = __builtin_bit_cast(unsigned int, a) + 0x8000u;
  unsigned int ub = __builtin_bit_cast(unsigned int, b) + 0x8000u;
  unsigned int r;
  asm("v_cvt_pk_bf16_f32 %0, %1, %2"
      : "=v"(r)
      : "v"(__builtin_bit_cast(float, ua)), "v"(__builtin_bit_cast(float, ub)));
  return r;
}

__device__ __forceinline__ float exp2a(float x) {
  return __builtin_amdgcn_exp2f(x);
}

// --------------------------------------------------------------- cast (merged)
__global__ __launch_bounds__(256) void cast_all_kernel(
    const float* __restrict__ wq, const float* __restrict__ wk,
    const float* __restrict__ wv, const float* __restrict__ wo,
    const float* __restrict__ xq, const float* __restrict__ xk,
    const float* __restrict__ xv, unsigned short* __restrict__ wbf,
    unsigned short* __restrict__ oxq, unsigned short* __restrict__ oxk,
    unsigned short* __restrict__ oxv) {
  const int job = blockIdx.y;
  const int i = blockIdx.x * 256 + threadIdx.x;  // float4 idx within slice
  const float* src;
  unsigned short* dst;
  size_t off;
  if (job < 4) {
    src = (job == 0) ? wq : (job == 1) ? wk : (job == 2) ? wv : wo;
    dst = wbf + (size_t)job * 1048576;
    off = (size_t)i;
  } else {
    const int xi = job - 4, z = xi >> 3, sl = xi & 7;
    src = (z == 0) ? xq : (z == 1) ? xk : xv;
    dst = (z == 0) ? oxq : (z == 1) ? oxk : oxv;
    off = (size_t)sl * 262144 + i;
  }
  float4 f = reinterpret_cast<const float4*>(src)[off];
  uint2 p;
  p.x = pkrne(f.x, f.y);
  p.y = pkrne(f.z, f.w);
  *reinterpret_cast<uint2*>(dst + off * 4) = p;
}

// ---------------------------------------------- Q/K/V projection (merged, bf16)
// z in {0,1}: C = Xbf @ W^T + bias -> [B,H,S,DK] scatter (Q scaled).
// z == 2  : V^T via swapped MFMA operands -> Vh[B,H,DK,S] coalesced.
// BK=64, GLL16 both operands, chunk swizzle phys = logical ^ (row&7).
__global__ __launch_bounds__(256) void gemm_qkvv_kernel(
    const unsigned short* __restrict__ Xq, const unsigned short* __restrict__ Xk,
    const unsigned short* __restrict__ Xv, const unsigned short* __restrict__ wbf,
    const float* __restrict__ bq, const float* __restrict__ bk,
    const float* __restrict__ bv, unsigned short* __restrict__ Qh,
    unsigned short* __restrict__ Kh, unsigned short* __restrict__ Vh) {
  const int z = blockIdx.z;
  const unsigned short* Xbf = (z == 0) ? Xq : (z == 1) ? Xk : Xv;
  const unsigned short* W = wbf + (size_t)z * 1048576;
  const float* bias = (z == 0) ? bq : (z == 1) ? bk : bv;
  const float qscale = (z == 0) ? 0.18033688011112042f : 1.0f;  // 0.125*log2e

  __shared__ __align__(16) unsigned short Asm_[128 * 64];
  __shared__ __align__(16) unsigned short Bsm_[128 * 64];

  const int t = threadIdx.x;
  const int lane = t & 63, w = t >> 6;
  const int g = lane >> 4, c = lane & 15;
  const int wm = (w >> 1) * 64, wn = (w & 1) * 64;
  const int n0 = (blockIdx.y & 7) * 128;
  const int m0 = (blockIdx.x * 8 + (blockIdx.y >> 3)) * 128;

  f32x4 acc[4][4];
#pragma unroll
  for (int i = 0; i < 4; i++)
#pragma unroll
    for (int j = 0; j < 4; j++) acc[i][j] = (f32x4)0.0f;

  const int blr = lane >> 3;
  const int bgc = (lane & 7) ^ blr;

  for (int kt = 0; kt < 16; ++kt) {
    const int k0 = kt * 64;
    __syncthreads();
#pragma unroll
    for (int i = 0; i < 4; i++) {
      int ii = w * 4 + i;
      const unsigned short* ga = Xbf + (size_t)(m0 + ii * 8 + blr) * 1024 + k0 + bgc * 8;
      GLL16(ga, &Asm_[ii * 512]);
      const unsigned short* gb = W + (size_t)(n0 + ii * 8 + blr) * 1024 + k0 + bgc * 8;
      GLL16(gb, &Bsm_[ii * 512]);
    }
    __syncthreads();

#pragma unroll
    for (int ks = 0; ks < 2; ks++) {
      s16x8 af[4], bfr[4];
#pragma unroll
      for (int mt = 0; mt < 4; mt++) {
        int r = wm + mt * 16 + c;
        af[mt] = *reinterpret_cast<const s16x8*>(&Asm_[r * 64 + (((ks * 4 + g) ^ (c & 7)) << 3)]);
      }
#pragma unroll
      for (int nt = 0; nt < 4; nt++) {
        int r = wn + nt * 16 + c;
        bfr[nt] = *reinterpret_cast<const s16x8*>(&Bsm_[r * 64 + (((ks * 4 + g) ^ (c & 7)) << 3)]);
      }
      if (z == 2) {
        // transposed: D[n][m]
#pragma unroll
        for (int nt = 0; nt < 4; nt++)
#pragma unroll
          for (int mt = 0; mt < 4; mt++)
            acc[nt][mt] = MFMA16(bfr[nt], af[mt], acc[nt][mt]);
      } else {
#pragma unroll
        for (int mt = 0; mt < 4; mt++)
#pragma unroll
          for (int nt = 0; nt < 4; nt++)
            acc[mt][nt] = MFMA16(af[mt], bfr[nt], acc[mt][nt]);
      }
    }
  }

  if (z == 2) {
    // epilogue: +bias, write Vh[B,H,DK,S]; lanes (c) -> consecutive s.
#pragma unroll
    for (int nt = 0; nt < 4; nt++)
#pragma unroll
      for (int mt = 0; mt < 4; mt++) {
        int m = m0 + wm + mt * 16 + c;   // global s index
        int b = m >> 11, s = m & 2047;
#pragma unroll
        for (int r = 0; r < 4; r++) {
          int n = n0 + wn + nt * 16 + g * 4 + r;  // feature
          int h = n >> 6, dk = n & 63;
          Vh[(((size_t)b * 16 + h) * 64 + dk) * 2048 + s] =
              f2bf(acc[nt][mt][r] + bv[n]);
        }
      }
  } else {
    unsigned short* dst = (z == 0) ? Qh : Kh;
#pragma unroll
    for (int mt = 0; mt < 4; mt++)
#pragma unroll
      for (int nt = 0; nt < 4; nt++) {
        int n = n0 + wn + nt * 16 + c;
        float bb = bias[n];
        int h = n >> 6, dk = n & 63;
#pragma unroll
        for (int r = 0; r < 4; r++) {
          int m = m0 + wm + mt * 16 + g * 4 + r;
          int b = m >> 11, s = m & 2047;
          dst[(((size_t)b * 16 + h) * 2048 + s) * 64 + dk] =
              f2bf((acc[mt][nt][r] + bb) * qscale);
        }
      }
  }
}

// ----------------------------------------------------------- output projection
// out(fp32)[8192,1024] = AO(bf16) @ Wo(bf16,[N,K]) + bo.  128x64 tile.
__global__ __launch_bounds__(256) void gemm_out_kernel(
    const unsigned short* __restrict__ AO, const unsigned short* __restrict__ Wo,
    const float* __restrict__ bo, float* __restrict__ out) {
  __shared__ __align__(16) unsigned short Asm_[128 * 64];
  __shared__ __align__(16) unsigned short Bsm_[64 * 64];

  const int t = threadIdx.x;
  const int lane = t & 63, w = t >> 6;
  const int g = lane >> 4, c = lane & 15;
  const int wm = (w >> 1) * 64, wn = (w & 1) * 32;
  const int n0 = (blockIdx.y & 15) * 64;
  const int m0 = (blockIdx.x * 8 + (blockIdx.y >> 4)) * 128;

  f32x4 acc[4][2];
#pragma unroll
  for (int i = 0; i < 4; i++)
#pragma unroll
    for (int j = 0; j < 2; j++) acc[i][j] = (f32x4)0.0f;

  const int blr = lane >> 3;
  const int bgc = (lane & 7) ^ blr;

  for (int kt = 0; kt < 16; ++kt) {
    const int k0 = kt * 64;
    __syncthreads();
#pragma unroll
    for (int i = 0; i < 4; i++) {
      int ii = w * 4 + i;
      const unsigned short* ga = AO + (size_t)(m0 + ii * 8 + blr) * 1024 + k0 + bgc * 8;
      GLL16(ga, &Asm_[ii * 512]);
    }
#pragma unroll
    for (int i = 0; i < 2; i++) {
      int ii = w * 2 + i;
      const unsigned short* gb = Wo + (size_t)(n0 + ii * 8 + blr) * 1024 + k0 + bgc * 8;
      GLL16(gb, &Bsm_[ii * 512]);
    }
    __syncthreads();

#pragma unroll
    for (int ks = 0; ks < 2; ks++) {
      s16x8 af[4], bfr[2];
#pragma unroll
      for (int mt = 0; mt < 4; mt++) {
        int r = wm + mt * 16 + c;
        af[mt] = *reinterpret_cast<const s16x8*>(&Asm_[r * 64 + (((ks * 4 + g) ^ (c & 7)) << 3)]);
      }
#pragma unroll
      for (int nt = 0; nt < 2; nt++) {
        int r = wn + nt * 16 + c;
        bfr[nt] = *reinterpret_cast<const s16x8*>(&Bsm_[r * 64 + (((ks * 4 + g) ^ (c & 7)) << 3)]);
      }
#pragma unroll
      for (int mt = 0; mt < 4; mt++)
#pragma unroll
        for (int nt = 0; nt < 2; nt++)
          acc[mt][nt] = MFMA16(af[mt], bfr[nt], acc[mt][nt]);
    }
  }

#pragma unroll
  for (int mt = 0; mt < 4; mt++)
#pragma unroll
    for (int nt = 0; nt < 2; nt++) {
      int n = n0 + wn + nt * 16 + c;
      float bb = bo[n];
#pragma unroll
      for (int r = 0; r < 4; r++) {
        int m = m0 + wm + mt * 16 + g * 4 + r;
        out[(size_t)m * 1024 + n] = acc[mt][nt][r] + bb;
      }
    }
}

// --------------------------------------------------------------- attention v12
// round-21 v11 + setprio(1) around MFMA clusters (T5): QK cluster, lacc+PV
// cluster. setprio(0) through the softmax VALU region so the other resident
// block's MFMA waves win SIMD arbitration during our VALU phase.
__global__ __launch_bounds__(512) void attn_kernel(
    const unsigned short* __restrict__ Qh, const unsigned short* __restrict__ Kh,
    const unsigned short* __restrict__ Vh, unsigned short* __restrict__ AO) {
  const int bh = blockIdx.x * 8 + (blockIdx.y >> 3);
  const int b = bh >> 4, h = bh & 15;
  const int q0 = (blockIdx.y & 7) * 256;
  const int t = threadIdx.x, lane = t & 63, w = t >> 6;
  const int lo = lane & 31, hi = lane >> 5;

  __shared__ __align__(16) unsigned short Ks[2][64 * 64];
  __shared__ __align__(16) unsigned short Vs[2][64 * 64];

  const size_t kvbase = (size_t)bh * 2048 * 64;

  s16x8 qb[4];
  {
    const unsigned short* qp = Qh + kvbase + (size_t)(q0 + w * 32 + lo) * 64;
#pragma unroll
    for (int ks = 0; ks < 4; ks++)
      qb[ks] = *reinterpret_cast<const s16x8*>(qp + ks * 16 + hi * 8);
  }

  s16x8 onesb;
  {
    uint4 u;
    u.x = 0x3F803F80u; u.y = 0x3F803F80u; u.z = 0x3F803F80u; u.w = 0x3F803F80u;
    onesb = *reinterpret_cast<const s16x8*>(&u);
  }

  f32x16 oacc[2], lacc;
  oacc[0] = (f32x16)0.0f; oacc[1] = (f32x16)0.0f; lacc = (f32x16)0.0f;

  const int srow = t >> 3;
  const int gch = (t & 7) ^ (srow & 7) ^ w;      // srow>>3 == w
  const unsigned short* Kg = Kh + kvbase + (size_t)srow * 64 + gch * 8;
  const unsigned short* Vg = Vh + kvbase + (size_t)srow * 2048 + gch * 8;

  const int rx0 = (lo & 7) ^ (lo >> 3);
  const int rx1 = (lo & 7) ^ (4 | (lo >> 3));

  // prologue: tile 0 -> buf 0 (vmcnt drained by the barrier)
  GLL16(Kg, &Ks[0][w * 512]);
  GLL16(Vg, &Vs[0][w * 512]);
  __syncthreads();

  for (int it = 0; it < 32; ++it) {
    const int cur = it & 1;
    if (it < 31) {
      const int kv = (it + 1) * 64;
      GLL16(Kg + (size_t)kv * 64, &Ks[cur ^ 1][w * 512]);
      GLL16(Vg + kv, &Vs[cur ^ 1][w * 512]);
    }

    // S^T = K·Q^T   (high priority: keep matrix pipe fed)
    f32x16 st[2];
    st[0] = (f32x16)0.0f; st[1] = (f32x16)0.0f;
    __builtin_amdgcn_s_setprio(1);
#pragma unroll
    for (int kb = 0; kb < 2; kb++) {
      const int rx = kb ? rx1 : rx0;
#pragma unroll
      for (int ks = 0; ks < 4; ks++) {
        s16x8 ka = *reinterpret_cast<const s16x8*>(
            &Ks[cur][(kb * 32 + lo) * 64 + (((ks * 2 + hi) ^ rx) << 3)]);
        st[kb] = MFMA32(ka, qb[ks], st[kb]);
      }
    }
    __builtin_amdgcn_s_setprio(0);

    // p = 2^s -> round-half-up bf16 pack (pkhu) -> permlane swap -> PV A-frags
    s16x8 pa[4];
#pragma unroll
    for (int kb = 0; kb < 2; kb++) {
      float e[16];
#pragma unroll
      for (int r = 0; r < 16; r++) e[r] = exp2a(st[kb][r]);
#pragma unroll
      for (int half = 0; half < 2; half++) {
        const float* eb = e + half * 8;
        unsigned int x1 = pkhu(eb[0], eb[1]);
        unsigned int x2 = pkhu(eb[2], eb[3]);
        unsigned int y1 = pkhu(eb[4], eb[5]);
        unsigned int y2 = pkhu(eb[6], eb[7]);
        asm volatile("v_permlane32_swap_b32 %0, %1" : "+v"(x1), "+v"(y1));
        asm volatile("v_permlane32_swap_b32 %0, %1" : "+v"(x2), "+v"(y2));
        uint4 u;
        u.x = x1; u.y = x2; u.z = y1; u.w = y2;
        pa[kb * 2 + half] = *reinterpret_cast<const s16x8*>(&u);
      }
    }

    // denominator + O += P·V  (high priority MFMA cluster)
    __builtin_amdgcn_s_setprio(1);
#pragma unroll
    for (int ks = 0; ks < 4; ks++) lacc = MFMA32(pa[ks], onesb, lacc);
#pragma unroll
    for (int ks = 0; ks < 4; ks++)
#pragma unroll
      for (int db = 0; db < 2; db++) {
        const int rx = db ? rx1 : rx0;
        s16x8 vb = *reinterpret_cast<const s16x8*>(
            &Vs[cur][(db * 32 + lo) * 64 + (((ks * 2 + hi) ^ rx) << 3)]);
        oacc[db] = MFMA32(pa[ks], vb, oacc[db]);
      }
    __builtin_amdgcn_s_setprio(0);

    __syncthreads();  // drains next-tile DMA; protects cur for reuse
  }

  // epilogue: normalize by lacc (same row layout as oacc), write AO bf16
#pragma unroll
  for (int r = 0; r < 16; r++) {
    float inv_r = 1.0f / lacc[r];
    int qr = (r & 3) + ((r >> 2) << 3) + (hi << 2);
    int srow_q = q0 + w * 32 + qr;
    size_t obase = ((size_t)b * 2048 + srow_q) * 1024 + (size_t)h * 64;
    AO[obase + lo]      = f2bf(oacc[0][r] * inv_r);
    AO[obase + 32 + lo] = f2bf(oacc[1][r] * inv_r);
  }
}

// ---------------------------------------------------------------- launcher
extern "C" void kernel_launch(void* const* d_in, const int* in_sizes, int n_in,
                              void* d_out, int out_size, void* d_ws, size_t ws_size,
                              hipStream_t stream) {
  const float* query = (const float*)d_in[0];
  const float* key   = (const float*)d_in[1];
  const float* value = (const float*)d_in[2];
  const float* Wq = (const float*)d_in[3];
  const float* bq = (const float*)d_in[4];
  const float* Wk = (const float*)d_in[5];
  const float* bk = (const float*)d_in[6];
  const float* Wv = (const float*)d_in[7];
  const float* bv = (const float*)d_in[8];
  const float* Wo = (const float*)d_in[9];
  const float* bo = (const float*)d_in[10];

  uint8_t* wsb = (uint8_t*)d_ws;
  unsigned short* wbf = (unsigned short*)wsb;                      // 4 x 1M bf16
  unsigned short* Qh  = (unsigned short*)(wsb + 8388608);
  unsigned short* Kh  = (unsigned short*)(wsb + 8388608 + 16777216);
  unsigned short* Vh  = (unsigned short*)(wsb + 8388608 + 2 * 16777216);
  unsigned short* AO  = (unsigned short*)(wsb + 8388608 + 3 * 16777216);
  // bf16 X staging: Xq in AO region; Xk/Xv in d_out (scratch until gemm_out)
  unsigned short* Xq = AO;
  unsigned short* Xk = (unsigned short*)d_out;
  unsigned short* Xv = (unsigned short*)d_out + 8388608;

  cast_all_kernel<<<dim3(1024, 28), dim3(256), 0, stream>>>(
      Wq, Wk, Wv, Wo, query, key, value, wbf, Xq, Xk, Xv);
  gemm_qkvv_kernel<<<dim3(8, 64, 3), dim3(256), 0, stream>>>(
      Xq, Xk, Xv, wbf, bq, bk, bv, Qh, Kh, Vh);
  attn_kernel<<<dim3(8, 64), dim3(512), 0, stream>>>(Qh, Kh, Vh, AO);
  gemm_out_kernel<<<dim3(8, 128), dim3(256), 0, stream>>>(
      AO, wbf + (size_t)3 * 1048576, bo, (float*)d_out);
}

// Round 23
// 199.339 us; speedup vs baseline: 1.0861x; 1.0063x over previous
//
#include <hip/hip_runtime.h>
#include <hip/hip_bf16.h>
#include <stdint.h>

// MHA fused pipeline, MI355X gfx950.
// B=4 S=2048 D=1024 H=16 DK=64.  fp32 in/out, bf16 MFMA internally.
//
// ws layout (bytes):
//   [0,        8388608)   wbf   : bf16 weights [4][1024][1024] order q,k,v,o
//   [8388608,  25165824)  Qh    : bf16 [B,H,S,DK]  (Q pre-scaled by 0.125*log2e)
//   [25165824, 41943040)  Kh    : bf16 [B,H,S,DK]
//   [41943040, 58720256)  Vh    : bf16 [B,H,DK,S]  (TRANSPOSED)
//   [58720256, 75497472)  AO    : bf16, DUAL USE: Xq staging -> attn output
// d_out (fp32) is scratch for Xk/Xv bf16 during the QKV phase; fully
// overwritten by gemm_out at the end (deterministic).
//
// Round 23: attn KVBLK=128 as TWO 64-sub-tiles per barrier period — 16
// barriers instead of 32, and sub-tile 0's PV is register-independent of
// sub-tile 1's QK (compiler-interleavable ILP without round-17's extra
// state). LDS 64KB; residency grid-limited at 2 blocks/CU so no occupancy
// loss. Same per-issue swizzle ((j*64+srow)>>3 & 7 == w, gch unchanged).
// Everything else = round-22 (200.6us best: pkhu pack, setprio clusters).
//
// NUMERICS: f32->bf16 casts feeding GEMM operands use explicit RNE bit math.
// Attention P uses pkhu (+0x8000 bias + truncating v_cvt_pk_bf16_f32 =
// round-half-up, validated rounds 21-22). RULE#20: no runtime-indexed
// register arrays. Softmax denominator = MFMA ones row-sum of the SAME P.

using f32x4  = __attribute__((ext_vector_type(4))) float;
using f32x16 = __attribute__((ext_vector_type(16))) float;
using s16x8  = __attribute__((ext_vector_type(8))) short;
using u16x8  = __attribute__((ext_vector_type(8))) unsigned short;
using u16x4  = __attribute__((ext_vector_type(4))) unsigned short;

#define MFMA16(a, b, c) __builtin_amdgcn_mfma_f32_16x16x32_bf16((a), (b), (c), 0, 0, 0)
#define MFMA32(a, b, c) __builtin_amdgcn_mfma_f32_32x32x16_bf16((a), (b), (c), 0, 0, 0)

#define GLL16(gptr, lptr)                                                      \
  __builtin_amdgcn_global_load_lds(                                            \
      (const __attribute__((address_space(1))) void*)(gptr),                   \
      (__attribute__((address_space(3))) void*)(lptr), 16, 0, 0)

__device__ __forceinline__ unsigned short f2bf(float f) {
  union { __hip_bfloat16 h; unsigned short u; } cv;
  cv.h = __float2bfloat16(f);
  return cv.u;
}

// explicit RNE f32->bf16 pair pack (bit-identical to __float2bfloat16, finite)
__device__ __forceinline__ unsigned int pkrne(float a, float b) {
  unsigned int ua = __builtin_bit_cast(unsigned int, a);
  unsigned int ub = __builtin_bit_cast(unsigned int, b);
  ua = ua + 0x7FFFu + ((ua >> 16) & 1u);
  ub = ub + 0x7FFFu + ((ub >> 16) & 1u);
  return __builtin_amdgcn_perm(ub, ua, 0x07060302u);
}

// round-half-up f32->bf16 pair pack for POSITIVE finite values: integer
// +0x8000 bias, then truncating v_cvt_pk_bf16_f32. 3 VALU ops vs pkrne's 7.
__device__ __forceinline__ unsigned int pkhu(float a, float b) {
  unsigned int ua = __builtin_bit_cast(unsigned int, a) + 0x8000u;
  unsigned int ub = __builtin_bit_cast(unsigned int, b) + 0x8000u;
  unsigned int r;
  asm("v_cvt_pk_bf16_f32 %0, %1, %2"
      : "=v"(r)
      : "v"(__builtin_bit_cast(float, ua)), "v"(__builtin_bit_cast(float, ub)));
  return r;
}

__device__ __forceinline__ float exp2a(float x) {
  return __builtin_amdgcn_exp2f(x);
}

// --------------------------------------------------------------- cast (merged)
__global__ __launch_bounds__(256) void cast_all_kernel(
    const float* __restrict__ wq, const float* __restrict__ wk,
    const float* __restrict__ wv, const float* __restrict__ wo,
    const float* __restrict__ xq, const float* __restrict__ xk,
    const float* __restrict__ xv, unsigned short* __restrict__ wbf,
    unsigned short* __restrict__ oxq, unsigned short* __restrict__ oxk,
    unsigned short* __restrict__ oxv) {
  const int job = blockIdx.y;
  const int i = blockIdx.x * 256 + threadIdx.x;  // float4 idx within slice
  const float* src;
  unsigned short* dst;
  size_t off;
  if (job < 4) {
    src = (job == 0) ? wq : (job == 1) ? wk : (job == 2) ? wv : wo;
    dst = wbf + (size_t)job * 1048576;
    off = (size_t)i;
  } else {
    const int xi = job - 4, z = xi >> 3, sl = xi & 7;
    src = (z == 0) ? xq : (z == 1) ? xk : xv;
    dst = (z == 0) ? oxq : (z == 1) ? oxk : oxv;
    off = (size_t)sl * 262144 + i;
  }
  float4 f = reinterpret_cast<const float4*>(src)[off];
  uint2 p;
  p.x = pkrne(f.x, f.y);
  p.y = pkrne(f.z, f.w);
  *reinterpret_cast<uint2*>(dst + off * 4) = p;
}

// ---------------------------------------------- Q/K/V projection (merged, bf16)
// z in {0,1}: C = Xbf @ W^T + bias -> [B,H,S,DK] scatter (Q scaled).
// z == 2  : V^T via swapped MFMA operands -> Vh[B,H,DK,S] coalesced.
// BK=64, GLL16 both operands, chunk swizzle phys = logical ^ (row&7).
__global__ __launch_bounds__(256) void gemm_qkvv_kernel(
    const unsigned short* __restrict__ Xq, const unsigned short* __restrict__ Xk,
    const unsigned short* __restrict__ Xv, const unsigned short* __restrict__ wbf,
    const float* __restrict__ bq, const float* __restrict__ bk,
    const float* __restrict__ bv, unsigned short* __restrict__ Qh,
    unsigned short* __restrict__ Kh, unsigned short* __restrict__ Vh) {
  const int z = blockIdx.z;
  const unsigned short* Xbf = (z == 0) ? Xq : (z == 1) ? Xk : Xv;
  const unsigned short* W = wbf + (size_t)z * 1048576;
  const float* bias = (z == 0) ? bq : (z == 1) ? bk : bv;
  const float qscale = (z == 0) ? 0.18033688011112042f : 1.0f;  // 0.125*log2e

  __shared__ __align__(16) unsigned short Asm_[128 * 64];
  __shared__ __align__(16) unsigned short Bsm_[128 * 64];

  const int t = threadIdx.x;
  const int lane = t & 63, w = t >> 6;
  const int g = lane >> 4, c = lane & 15;
  const int wm = (w >> 1) * 64, wn = (w & 1) * 64;
  const int n0 = (blockIdx.y & 7) * 128;
  const int m0 = (blockIdx.x * 8 + (blockIdx.y >> 3)) * 128;

  f32x4 acc[4][4];
#pragma unroll
  for (int i = 0; i < 4; i++)
#pragma unroll
    for (int j = 0; j < 4; j++) acc[i][j] = (f32x4)0.0f;

  const int blr = lane >> 3;
  const int bgc = (lane & 7) ^ blr;

  for (int kt = 0; kt < 16; ++kt) {
    const int k0 = kt * 64;
    __syncthreads();
#pragma unroll
    for (int i = 0; i < 4; i++) {
      int ii = w * 4 + i;
      const unsigned short* ga = Xbf + (size_t)(m0 + ii * 8 + blr) * 1024 + k0 + bgc * 8;
      GLL16(ga, &Asm_[ii * 512]);
      const unsigned short* gb = W + (size_t)(n0 + ii * 8 + blr) * 1024 + k0 + bgc * 8;
      GLL16(gb, &Bsm_[ii * 512]);
    }
    __syncthreads();

#pragma unroll
    for (int ks = 0; ks < 2; ks++) {
      s16x8 af[4], bfr[4];
#pragma unroll
      for (int mt = 0; mt < 4; mt++) {
        int r = wm + mt * 16 + c;
        af[mt] = *reinterpret_cast<const s16x8*>(&Asm_[r * 64 + (((ks * 4 + g) ^ (c & 7)) << 3)]);
      }
#pragma unroll
      for (int nt = 0; nt < 4; nt++) {
        int r = wn + nt * 16 + c;
        bfr[nt] = *reinterpret_cast<const s16x8*>(&Bsm_[r * 64 + (((ks * 4 + g) ^ (c & 7)) << 3)]);
      }
      if (z == 2) {
        // transposed: D[n][m]
#pragma unroll
        for (int nt = 0; nt < 4; nt++)
#pragma unroll
          for (int mt = 0; mt < 4; mt++)
            acc[nt][mt] = MFMA16(bfr[nt], af[mt], acc[nt][mt]);
      } else {
#pragma unroll
        for (int mt = 0; mt < 4; mt++)
#pragma unroll
          for (int nt = 0; nt < 4; nt++)
            acc[mt][nt] = MFMA16(af[mt], bfr[nt], acc[mt][nt]);
      }
    }
  }

  if (z == 2) {
    // epilogue: +bias, write Vh[B,H,DK,S]; lanes (c) -> consecutive s.
#pragma unroll
    for (int nt = 0; nt < 4; nt++)
#pragma unroll
      for (int mt = 0; mt < 4; mt++) {
        int m = m0 + wm + mt * 16 + c;   // global s index
        int b = m >> 11, s = m & 2047;
#pragma unroll
        for (int r = 0; r < 4; r++) {
          int n = n0 + wn + nt * 16 + g * 4 + r;  // feature
          int h = n >> 6, dk = n & 63;
          Vh[(((size_t)b * 16 + h) * 64 + dk) * 2048 + s] =
              f2bf(acc[nt][mt][r] + bv[n]);
        }
      }
  } else {
    unsigned short* dst = (z == 0) ? Qh : Kh;
#pragma unroll
    for (int mt = 0; mt < 4; mt++)
#pragma unroll
      for (int nt = 0; nt < 4; nt++) {
        int n = n0 + wn + nt * 16 + c;
        float bb = bias[n];
        int h = n >> 6, dk = n & 63;
#pragma unroll
        for (int r = 0; r < 4; r++) {
          int m = m0 + wm + mt * 16 + g * 4 + r;
          int b = m >> 11, s = m & 2047;
          dst[(((size_t)b * 16 + h) * 2048 + s) * 64 + dk] =
              f2bf((acc[mt][nt][r] + bb) * qscale);
        }
      }
  }
}

// ----------------------------------------------------------- output projection
// out(fp32)[8192,1024] = AO(bf16) @ Wo(bf16,[N,K]) + bo.  128x64 tile.
__global__ __launch_bounds__(256) void gemm_out_kernel(
    const unsigned short* __restrict__ AO, const unsigned short* __restrict__ Wo,
    const float* __restrict__ bo, float* __restrict__ out) {
  __shared__ __align__(16) unsigned short Asm_[128 * 64];
  __shared__ __align__(16) unsigned short Bsm_[64 * 64];

  const int t = threadIdx.x;
  const int lane = t & 63, w = t >> 6;
  const int g = lane >> 4, c = lane & 15;
  const int wm = (w >> 1) * 64, wn = (w & 1) * 32;
  const int n0 = (blockIdx.y & 15) * 64;
  const int m0 = (blockIdx.x * 8 + (blockIdx.y >> 4)) * 128;

  f32x4 acc[4][2];
#pragma unroll
  for (int i = 0; i < 4; i++)
#pragma unroll
    for (int j = 0; j < 2; j++) acc[i][j] = (f32x4)0.0f;

  const int blr = lane >> 3;
  const int bgc = (lane & 7) ^ blr;

  for (int kt = 0; kt < 16; ++kt) {
    const int k0 = kt * 64;
    __syncthreads();
#pragma unroll
    for (int i = 0; i < 4; i++) {
      int ii = w * 4 + i;
      const unsigned short* ga = AO + (size_t)(m0 + ii * 8 + blr) * 1024 + k0 + bgc * 8;
      GLL16(ga, &Asm_[ii * 512]);
    }
#pragma unroll
    for (int i = 0; i < 2; i++) {
      int ii = w * 2 + i;
      const unsigned short* gb = Wo + (size_t)(n0 + ii * 8 + blr) * 1024 + k0 + bgc * 8;
      GLL16(gb, &Bsm_[ii * 512]);
    }
    __syncthreads();

#pragma unroll
    for (int ks = 0; ks < 2; ks++) {
      s16x8 af[4], bfr[2];
#pragma unroll
      for (int mt = 0; mt < 4; mt++) {
        int r = wm + mt * 16 + c;
        af[mt] = *reinterpret_cast<const s16x8*>(&Asm_[r * 64 + (((ks * 4 + g) ^ (c & 7)) << 3)]);
      }
#pragma unroll
      for (int nt = 0; nt < 2; nt++) {
        int r = wn + nt * 16 + c;
        bfr[nt] = *reinterpret_cast<const s16x8*>(&Bsm_[r * 64 + (((ks * 4 + g) ^ (c & 7)) << 3)]);
      }
#pragma unroll
      for (int mt = 0; mt < 4; mt++)
#pragma unroll
        for (int nt = 0; nt < 2; nt++)
          acc[mt][nt] = MFMA16(af[mt], bfr[nt], acc[mt][nt]);
    }
  }

#pragma unroll
  for (int mt = 0; mt < 4; mt++)
#pragma unroll
    for (int nt = 0; nt < 2; nt++) {
      int n = n0 + wn + nt * 16 + c;
      float bb = bo[n];
#pragma unroll
      for (int r = 0; r < 4; r++) {
        int m = m0 + wm + mt * 16 + g * 4 + r;
        out[(size_t)m * 1024 + n] = acc[mt][nt][r] + bb;
      }
    }
}

// --------------------------------------------------------------- attention v13
// round-22 v12 body, KVBLK=128 as two 64-sub-tiles per barrier period:
// stage 128 KV rows (4 GLL16/wave), run sub-tile body j=0 then j=1, one
// barrier. 16 barriers (was 32); sub-tile 0's PV independent of sub-tile 1's
// QK -> compiler-interleavable cross-pipe ILP with no persistent extra state.
__global__ __launch_bounds__(512) void attn_kernel(
    const unsigned short* __restrict__ Qh, const unsigned short* __restrict__ Kh,
    const unsigned short* __restrict__ Vh, unsigned short* __restrict__ AO) {
  const int bh = blockIdx.x * 8 + (blockIdx.y >> 3);
  const int b = bh >> 4, h = bh & 15;
  const int q0 = (blockIdx.y & 7) * 256;
  const int t = threadIdx.x, lane = t & 63, w = t >> 6;
  const int lo = lane & 31, hi = lane >> 5;

  // [buf][subtile][64x64]
  __shared__ __align__(16) unsigned short Ks[2][2][64 * 64];
  __shared__ __align__(16) unsigned short Vs[2][2][64 * 64];

  const size_t kvbase = (size_t)bh * 2048 * 64;

  s16x8 qb[4];
  {
    const unsigned short* qp = Qh + kvbase + (size_t)(q0 + w * 32 + lo) * 64;
#pragma unroll
    for (int ks = 0; ks < 4; ks++)
      qb[ks] = *reinterpret_cast<const s16x8*>(qp + ks * 16 + hi * 8);
  }

  s16x8 onesb;
  {
    uint4 u;
    u.x = 0x3F803F80u; u.y = 0x3F803F80u; u.z = 0x3F803F80u; u.w = 0x3F803F80u;
    onesb = *reinterpret_cast<const s16x8*>(&u);
  }

  f32x16 oacc[2], lacc;
  oacc[0] = (f32x16)0.0f; oacc[1] = (f32x16)0.0f; lacc = (f32x16)0.0f;

  // staging map: srow = t>>3 (0..63); for sub-tile j the global row is
  // j*64+srow, and ((j*64+srow)>>3)&7 == w, (j*64+srow)&7 == srow&7 — so the
  // pre-swizzled chunk gch is the SAME for both sub-issues.
  const int srow = t >> 3;
  const int gch = (t & 7) ^ (srow & 7) ^ w;
  const unsigned short* Kg = Kh + kvbase + (size_t)srow * 64 + gch * 8;
  const unsigned short* Vg = Vh + kvbase + (size_t)srow * 2048 + gch * 8;

  const int rx0 = (lo & 7) ^ (lo >> 3);
  const int rx1 = (lo & 7) ^ (4 | (lo >> 3));

  // prologue: KV rows [0,128) -> buf 0 (drained by the barrier)
  GLL16(Kg, &Ks[0][0][w * 512]);
  GLL16(Kg + 4096, &Ks[0][1][w * 512]);
  GLL16(Vg, &Vs[0][0][w * 512]);
  GLL16(Vg + 64, &Vs[0][1][w * 512]);
  __syncthreads();

  for (int it = 0; it < 16; ++it) {
    const int cur = it & 1;
    if (it < 15) {
      const int nb = cur ^ 1;
      const size_t ko = (size_t)(it + 1) * 8192;  // 128 rows * 64 shorts
      const int vo = (it + 1) * 128;              // 128 s-columns
      GLL16(Kg + ko, &Ks[nb][0][w * 512]);
      GLL16(Kg + ko + 4096, &Ks[nb][1][w * 512]);
      GLL16(Vg + vo, &Vs[nb][0][w * 512]);
      GLL16(Vg + vo + 64, &Vs[nb][1][w * 512]);
    }

#pragma unroll
    for (int j = 0; j < 2; ++j) {
      // S^T = K·Q^T   (high priority: keep matrix pipe fed)
      f32x16 st[2];
      st[0] = (f32x16)0.0f; st[1] = (f32x16)0.0f;
      __builtin_amdgcn_s_setprio(1);
#pragma unroll
      for (int kb = 0; kb < 2; kb++) {
        const int rx = kb ? rx1 : rx0;
#pragma unroll
        for (int ks = 0; ks < 4; ks++) {
          s16x8 ka = *reinterpret_cast<const s16x8*>(
              &Ks[cur][j][(kb * 32 + lo) * 64 + (((ks * 2 + hi) ^ rx) << 3)]);
          st[kb] = MFMA32(ka, qb[ks], st[kb]);
        }
      }
      __builtin_amdgcn_s_setprio(0);

      // p = 2^s -> round-half-up pack (pkhu) -> permlane swap -> PV A-frags
      s16x8 pa[4];
#pragma unroll
      for (int kb = 0; kb < 2; kb++) {
        float e[16];
#pragma unroll
        for (int r = 0; r < 16; r++) e[r] = exp2a(st[kb][r]);
#pragma unroll
        for (int half = 0; half < 2; half++) {
          const float* eb = e + half * 8;
          unsigned int x1 = pkhu(eb[0], eb[1]);
          unsigned int x2 = pkhu(eb[2], eb[3]);
          unsigned int y1 = pkhu(eb[4], eb[5]);
          unsigned int y2 = pkhu(eb[6], eb[7]);
          asm volatile("v_permlane32_swap_b32 %0, %1" : "+v"(x1), "+v"(y1));
          asm volatile("v_permlane32_swap_b32 %0, %1" : "+v"(x2), "+v"(y2));
          uint4 u;
          u.x = x1; u.y = x2; u.z = y1; u.w = y2;
          pa[kb * 2 + half] = *reinterpret_cast<const s16x8*>(&u);
        }
      }

      // denominator + O += P·V  (high priority MFMA cluster)
      __builtin_amdgcn_s_setprio(1);
#pragma unroll
      for (int ks = 0; ks < 4; ks++) lacc = MFMA32(pa[ks], onesb, lacc);
#pragma unroll
      for (int ks = 0; ks < 4; ks++)
#pragma unroll
        for (int db = 0; db < 2; db++) {
          const int rx = db ? rx1 : rx0;
          s16x8 vb = *reinterpret_cast<const s16x8*>(
              &Vs[cur][j][(db * 32 + lo) * 64 + (((ks * 2 + hi) ^ rx) << 3)]);
          oacc[db] = MFMA32(pa[ks], vb, oacc[db]);
        }
      __builtin_amdgcn_s_setprio(0);
    }

    __syncthreads();  // drains next-tile DMA; protects cur for reuse
  }

  // epilogue: normalize by lacc (same row layout as oacc), write AO bf16
#pragma unroll
  for (int r = 0; r < 16; r++) {
    float inv_r = 1.0f / lacc[r];
    int qr = (r & 3) + ((r >> 2) << 3) + (hi << 2);
    int srow_q = q0 + w * 32 + qr;
    size_t obase = ((size_t)b * 2048 + srow_q) * 1024 + (size_t)h * 64;
    AO[obase + lo]      = f2bf(oacc[0][r] * inv_r);
    AO[obase + 32 + lo] = f2bf(oacc[1][r] * inv_r);
  }
}

// ---------------------------------------------------------------- launcher
extern "C" void kernel_launch(void* const* d_in, const int* in_sizes, int n_in,
                              void* d_out, int out_size, void* d_ws, size_t ws_size,
                              hipStream_t stream) {
  const float* query = (const float*)d_in[0];
  const float* key   = (const float*)d_in[1];
  const float* value = (const float*)d_in[2];
  const float* Wq = (const float*)d_in[3];
  const float* bq = (const float*)d_in[4];
  const float* Wk = (const float*)d_in[5];
  const float* bk = (const float*)d_in[6];
  const float* Wv = (const float*)d_in[7];
  const float* bv = (const float*)d_in[8];
  const float* Wo = (const float*)d_in[9];
  const float* bo = (const float*)d_in[10];

  uint8_t* wsb = (uint8_t*)d_ws;
  unsigned short* wbf = (unsigned short*)wsb;                      // 4 x 1M bf16
  unsigned short* Qh  = (unsigned short*)(wsb + 8388608);
  unsigned short* Kh  = (unsigned short*)(wsb + 8388608 + 16777216);
  unsigned short* Vh  = (unsigned short*)(wsb + 8388608 + 2 * 16777216);
  unsigned short* AO  = (unsigned short*)(wsb + 8388608 + 3 * 16777216);
  // bf16 X staging: Xq in AO region; Xk/Xv in d_out (scratch until gemm_out)
  unsigned short* Xq = AO;
  unsigned short* Xk = (unsigned short*)d_out;
  unsigned short* Xv = (unsigned short*)d_out + 8388608;

  cast_all_kernel<<<dim3(1024, 28), dim3(256), 0, stream>>>(
      Wq, Wk, Wv, Wo, query, key, value, wbf, Xq, Xk, Xv);
  gemm_qkvv_kernel<<<dim3(8, 64, 3), dim3(256), 0, stream>>>(
      Xq, Xk, Xv, wbf, bq, bk, bv, Qh, Kh, Vh);
  attn_kernel<<<dim3(8, 64), dim3(512), 0, stream>>>(Qh, Kh, Vh, AO);
  gemm_out_kernel<<<dim3(8, 128), dim3(256), 0, stream>>>(
      AO, wbf + (size_t)3 * 1048576, bo, (float*)d_out);
}